// Round 10
// baseline (360106.396 us; speedup 1.0000x reference)
//
#include <hip/hip_runtime.h>

// ResRGCN: h=x@W1+b1; 2x {per-(dst,rel) mean aggr -> [h|agg]@[root;W_r]+bias, h+=relu}; out=h@W2+b2
// Layer 3 of the reference is dead (output discarded) and is skipped.
// Edges counting-sorted by key = dst*8+type; each wave's 4 nodes own one flat
// contiguous edge range (33 boundaries). k_conv: 8-slot x 8-edge global_load_lds
// pipeline (depth-7 lookahead, counted vmcnt) -- r10 depth probe: r5/r6/r9 all
// converge at ~100us/conv regardless of gather engine, testing whether in-flight
// depth or a service-rate wall governs. lin2 fused into conv-2 epilogue (h3 never
// hits HBM); scan3 folded into scatter/conv boundary loads.

#define HDIM 64
#define RREL 8
#define KCAT 576   // 64 (root/self) + 8*64 (relations)
#define NPB  16    // nodes per workgroup in MFMA kernels
#define APAD 584   // padded LDS row
#define CH   8     // edges per batch (1 DMA x 8 rows)
#define SLOTS 8    // pipeline slots per wave

typedef short  short8 __attribute__((ext_vector_type(8)));
typedef __bf16 bf16x8 __attribute__((ext_vector_type(8)));
typedef float  f32x4  __attribute__((ext_vector_type(4)));
typedef unsigned int uint;
typedef unsigned short ushort;

#define GLB(p) ((const __attribute__((address_space(1))) void*)(p))
#define LDS(p) ((__attribute__((address_space(3))) void*)(p))

static __device__ __forceinline__ ushort f2bf(float f) {
  uint u = __builtin_bit_cast(uint, f);
  u += 0x7FFFu + ((u >> 16) & 1u);
  return (ushort)(u >> 16);
}
static __device__ __forceinline__ float bf2f(ushort s) {
  uint u = ((uint)s) << 16;
  return __builtin_bit_cast(float, u);
}

// ---- weight prep: wt_lin1[j][k]=lin1_w[k][j]; wt_conv[l][j][k] = cat(root_l, W_r)^T in bf16
__global__ void k_prep_wt(const float* __restrict__ lin1_w, const float* __restrict__ bases,
                          const float* __restrict__ comp, const float* __restrict__ root,
                          ushort* __restrict__ wt_lin1, ushort* __restrict__ wt_conv) {
  int t = blockIdx.x * 256 + threadIdx.x;
  if (t < HDIM * HDIM) {
    int j = t >> 6, k = t & 63;
    wt_lin1[t] = f2bf(lin1_w[k * HDIM + j]);
  }
  if (t < 2 * HDIM * KCAT) {
    int l = t / (HDIM * KCAT);
    int rem = t - l * (HDIM * KCAT);
    int j = rem / KCAT;
    int k = rem - j * KCAT;
    float v;
    if (k < HDIM) {
      v = root[(l * HDIM + k) * HDIM + j];
    } else {
      int r = (k - HDIM) >> 6;
      int i = (k - HDIM) & 63;
      v = 0.f;
      #pragma unroll
      for (int b = 0; b < 4; ++b)
        v += comp[(l * RREL + r) * 4 + b] * bases[((l * 4 + b) * HDIM + i) * HDIM + j];
    }
    wt_conv[t] = f2bf(v);
  }
}

// ---- build CSR over keys = dst*8 + type (M = 8N bins)
__global__ void k_hist(const int* __restrict__ dst, const int* __restrict__ et, int E,
                       uint* __restrict__ deg) {
  int e = blockIdx.x * 256 + threadIdx.x;
  if (e < E) atomicAdd(&deg[dst[e] * RREL + et[e]], 1u);
}

__global__ void k_scan1(const uint* __restrict__ deg, uint* __restrict__ off,
                        uint* __restrict__ bsum, int M) {
  __shared__ uint s[256];
  int t = threadIdx.x;
  int base = blockIdx.x * 1024 + t * 4;
  uint v0 = 0, v1 = 0, v2 = 0, v3 = 0;
  if (base + 3 < M) {
    uint4 u = *(const uint4*)(deg + base);
    v0 = u.x; v1 = u.y; v2 = u.z; v3 = u.w;
  } else {
    if (base < M)     v0 = deg[base];
    if (base + 1 < M) v1 = deg[base + 1];
    if (base + 2 < M) v2 = deg[base + 2];
    if (base + 3 < M) v3 = deg[base + 3];
  }
  uint tsum = v0 + v1 + v2 + v3;
  s[t] = tsum;
  __syncthreads();
  for (int o = 1; o < 256; o <<= 1) {
    uint u = (t >= o) ? s[t - o] : 0u;
    __syncthreads();
    s[t] += u;
    __syncthreads();
  }
  uint ex = s[t] - tsum;
  if (base < M)     off[base]     = ex;
  if (base + 1 < M) off[base + 1] = ex + v0;
  if (base + 2 < M) off[base + 2] = ex + v0 + v1;
  if (base + 3 < M) off[base + 3] = ex + v0 + v1 + v2;
  if (t == 255) bsum[blockIdx.x] = s[255];
}

// scan2: exclusive-scan block sums in place; bsum[nblk]=0 so off[M]+bsum[M>>10]==E
__global__ void k_scan2(uint* __restrict__ bsum, uint* __restrict__ off, int nblk, int M, uint E) {
  __shared__ uint s[1024];
  int t = threadIdx.x;
  uint v = (t < nblk) ? bsum[t] : 0u;
  s[t] = v;
  __syncthreads();
  for (int o = 1; o < 1024; o <<= 1) {
    uint u = (t >= o) ? s[t - o] : 0u;
    __syncthreads();
    s[t] += u;
    __syncthreads();
  }
  if (t < nblk) bsum[t] = s[t] - v;
  if (t == nblk) bsum[t] = 0u;
  if (t == 0) off[M] = E;
}

// counting-sort scatter (scan3 folded: final offset = off + bsum[key>>10])
__global__ void k_scatter(const int* __restrict__ src, const int* __restrict__ dst,
                          const int* __restrict__ et, int E, const uint* __restrict__ off,
                          const uint* __restrict__ bsum, uint* __restrict__ deg,
                          uint* __restrict__ sorted) {
  int e = blockIdx.x * 256 + threadIdx.x;
  if (e < E) {
    int key = dst[e] * RREL + et[e];
    uint p = off[key] + bsum[key >> 10] + atomicSub(&deg[key], 1u) - 1u;
    sorted[p] = (uint)src[e];
  }
}

// ---- lin1: hb = bf16(x @ W1 + b1) (MFMA over K=64)
__global__ void k_lin1(const float* __restrict__ x, const ushort* __restrict__ wt,
                       const float* __restrict__ bias, ushort* __restrict__ hb, int N) {
  __shared__ ushort A[NPB][72];
  int nodebase = blockIdx.x * NPB;
  for (int i = threadIdx.x; i < NPB * HDIM; i += 256) {
    int nl = i >> 6, c = i & 63;
    int n = nodebase + nl;
    A[nl][c] = (n < N) ? f2bf(x[(size_t)n * HDIM + c]) : (ushort)0;
  }
  __syncthreads();
  int lane = threadIdx.x & 63, wid = threadIdx.x >> 6;
  int m16 = lane & 15, khi = lane >> 4;
  int colbase = wid * 16;
  f32x4 acc = {0.f, 0.f, 0.f, 0.f};
  #pragma unroll
  for (int kk = 0; kk < HDIM; kk += 32) {
    int k0 = kk + khi * 8;
    short8 av = *(const short8*)&A[m16][k0];
    short8 bv = *(const short8*)&wt[(colbase + m16) * HDIM + k0];
    acc = __builtin_amdgcn_mfma_f32_16x16x32_bf16(
        __builtin_bit_cast(bf16x8, av), __builtin_bit_cast(bf16x8, bv), acc, 0, 0, 0);
  }
  int j = colbase + m16;
  float bj = bias[j];
  #pragma unroll
  for (int r = 0; r < 4; ++r) {
    int nl = khi * 4 + r;
    int n = nodebase + nl;
    if (n < N) hb[(size_t)n * HDIM + j] = f2bf(acc[r] + bj);
  }
}

// ---- fused RGCN layer: 8-deep DMA pipeline + scalar boundary-flush walk.
//      last!=0: skip hb_out, fuse lin2 (out = h3 @ W2 + b2) in epilogue.
__global__ void __launch_bounds__(256, 3)
k_conv(const uint* __restrict__ off8, const uint* __restrict__ bsum,
       const uint* __restrict__ sorted, const ushort* __restrict__ hb_in,
       const ushort* __restrict__ wt, const float* __restrict__ bias,
       ushort* __restrict__ hb_out, int N, int last,
       const float* __restrict__ w2, const float* __restrict__ b2,
       float* __restrict__ out) {
  __shared__ ushort A[NPB][APAD];                            // 18.7 KB
  __shared__ __align__(16) ushort land[4][SLOTS][CH * HDIM]; // 32 KB
  __shared__ float accO[NPB][2];
  int nb0 = blockIdx.x * NPB;
  int lane = threadIdx.x & 63, wid = threadIdx.x >> 6;

  if (threadIdx.x < NPB * 2) accO[threadIdx.x >> 1][threadIdx.x & 1] = 0.f;

  // stage self rows: thread t -> row t>>4, chans (t&15)*4 (one uint2 each)
  {
    int tt = threadIdx.x;
    int nl = tt >> 4, c = (tt & 15) * 4;
    int n = nb0 + nl;
    uint2 v = {0u, 0u};
    if (n < N) v = *(const uint2*)&hb_in[(size_t)n * HDIM + c];
    *(uint2*)&A[nl][c] = v;
  }

  // this wave's 4 nodes: 33 boundaries in lanes 0..32 (scan3 folded: +bsum)
  int n0 = nb0 + wid * 4;
  uint M8 = (uint)N * RREL;
  uint bidx = (uint)n0 * RREL + (uint)lane;
  uint bl = (bidx > M8) ? M8 : bidx;               // clamp -> empty segs past N
  uint bvv = (lane < 33) ? (off8[bl] + bsum[bl >> 10]) : 0u;

  uint e0   = (uint)__builtin_amdgcn_readlane((int)bvv, 0);
  uint eEnd = (uint)__builtin_amdgcn_readlane((int)bvv, 32);
  uint tot  = eEnd - e0;
  uint nbat = (tot + CH - 1) / CH;
  uint cap  = nbat > 16u ? 16u : nbat;             // <=128 edges pipelined

  // preload up to 128 edge indices into 2 regs (2 coalesced loads; slack covers overrun)
  uint iv0 = sorted[e0 + (uint)lane];
  uint iv1 = sorted[e0 + 64u + (uint)lane];

  float run = 0.f;
  int ri = 0;
  uint prevb = e0;
  uint nextb = (uint)__builtin_amdgcn_readlane((int)bvv, 1);
  const ushort* hlane = hb_in + lane;

  int r8i = lane >> 3, c8 = lane & 7;
  auto stage = [&](uint t) {                       // addresses from regs -- no VMEM dep
    uint s = t & (SLOTS - 1u);
    int srcv = (int)((t < 8u) ? iv0 : iv1);        // q = t*8+r8i < 64 iff t < 8
    uint q = (t * 8u + (uint)r8i) & 63u;
    uint idx = (uint)__shfl(srcv, (int)q) & 0x1FFFFu;
    const ushort* sA = hb_in + ((size_t)idx << 6) + ((uint)c8 << 3);
    __builtin_amdgcn_global_load_lds(GLB(sA), LDS(&land[wid][s][0]), 16, 0, 0);
  };

  if (cap > 0) {
    // drain all prior vmem so counted waits see only our DMAs
    asm volatile("s_waitcnt vmcnt(0)" ::: "memory");
    __builtin_amdgcn_sched_barrier(0);
    for (uint i = 0; i < 7u && i < cap; ++i) stage(i);
    for (uint t = 0; t < cap; ++t) {
      uint rem = cap - 1u - t;
      if (rem > 6u) rem = 6u;
      switch (rem) {                               // counted wait: batch t landed
        case 6: asm volatile("s_waitcnt vmcnt(6)" ::: "memory"); break;
        case 5: asm volatile("s_waitcnt vmcnt(5)" ::: "memory"); break;
        case 4: asm volatile("s_waitcnt vmcnt(4)" ::: "memory"); break;
        case 3: asm volatile("s_waitcnt vmcnt(3)" ::: "memory"); break;
        case 2: asm volatile("s_waitcnt vmcnt(2)" ::: "memory"); break;
        case 1: asm volatile("s_waitcnt vmcnt(1)" ::: "memory"); break;
        default: asm volatile("s_waitcnt vmcnt(0)" ::: "memory"); break;
      }
      __builtin_amdgcn_sched_barrier(0);
      // read this batch's 8 values for this lane's channel
      float g[CH];
      const ushort* lb = &land[wid][t & (SLOTS - 1u)][lane];
      #pragma unroll
      for (int j = 0; j < CH; ++j) g[j] = bf2f(lb[j * HDIM]);
      if (t + 7u < cap) stage(t + 7u);             // refill slot (t-1)&7 (already consumed)
      // scalar boundary-flush walk
      uint base = e0 + t * CH;
      uint m = eEnd - base;                        // scalar
      if (m > CH) m = CH;
      #pragma unroll
      for (int j = 0; j < CH; ++j) {
        if ((uint)j < m) {                         // scalar guard
          uint pos = base + (uint)j;
          while (pos >= nextb) {                   // scalar flush walk
            float mean = run * __builtin_amdgcn_rcpf(fmaxf((float)(nextb - prevb), 1.0f));
            int row = (wid << 2) + (ri >> 3);
            A[row][HDIM + (ri & 7) * HDIM + lane] = f2bf(mean);
            run = 0.f;
            ++ri;
            prevb = nextb;
            nextb = (uint)__builtin_amdgcn_readlane((int)bvv, ri + 1);
          }
          run += g[j];
        }
      }
    }
  }
  asm volatile("" ::: "memory");
  // serial fallback for >128-edge waves (P ~ 1e-10, correctness only)
  for (uint e = e0 + cap * (uint)CH; e < eEnd; ++e) {
    uint idx = sorted[e] & 0x1FFFFu;
    float v = bf2f(hlane[(size_t)idx << 6]);
    while (e >= nextb) {
      float mean = run * __builtin_amdgcn_rcpf(fmaxf((float)(nextb - prevb), 1.0f));
      int row = (wid << 2) + (ri >> 3);
      A[row][HDIM + (ri & 7) * HDIM + lane] = f2bf(mean);
      run = 0.f;
      ++ri;
      prevb = nextb;
      nextb = (uint)__builtin_amdgcn_readlane((int)bvv, ri + 1);
    }
    run += v;
  }
  while (ri < 32) {                                // trailing flushes (incl. empty)
    float mean = run * __builtin_amdgcn_rcpf(fmaxf((float)(nextb - prevb), 1.0f));
    int row = (wid << 2) + (ri >> 3);
    A[row][HDIM + (ri & 7) * HDIM + lane] = f2bf(mean);
    run = 0.f;
    ++ri;
    prevb = nextb;
    if (ri < 32) nextb = (uint)__builtin_amdgcn_readlane((int)bvv, ri + 1);
  }
  __syncthreads();

  // MFMA: [16 x 576] @ [576 x 64]
  int m16 = lane & 15, khi = lane >> 4;
  int colbase = wid * 16;
  f32x4 acc = {0.f, 0.f, 0.f, 0.f};
  #pragma unroll
  for (int kk = 0; kk < KCAT; kk += 32) {
    int k0 = kk + khi * 8;
    short8 av = *(const short8*)&A[m16][k0];
    short8 bv = *(const short8*)&wt[(uint)(colbase + m16) * KCAT + k0];
    acc = __builtin_amdgcn_mfma_f32_16x16x32_bf16(
        __builtin_bit_cast(bf16x8, av), __builtin_bit_cast(bf16x8, bv), acc, 0, 0, 0);
  }
  int j = colbase + m16;
  float bj = bias[j];
  if (!last) {
    #pragma unroll
    for (int r = 0; r < 4; ++r) {
      int nl = khi * 4 + r;
      int n = nb0 + nl;
      if (n < N) {
        float hs = bf2f(A[nl][j]);                 // self row (residual base)
        float hn = hs + fmaxf(acc[r] + bj, 0.f);
        hb_out[(uint)n * HDIM + j] = f2bf(hn);
      }
    }
  } else {
    // fused lin2: out[n] = h3[n] @ W2 + b2 (shfl-reduce over 16 col-lanes, LDS combine)
    float w0 = w2[j * 2], w1 = w2[j * 2 + 1];
    #pragma unroll
    for (int r = 0; r < 4; ++r) {
      int nl = khi * 4 + r;
      int n = nb0 + nl;
      float hn = 0.f;
      if (n < N) {
        float hs = bf2f(A[nl][j]);
        hn = hs + fmaxf(acc[r] + bj, 0.f);
      }
      float p0 = hn * w0, p1 = hn * w1;
      #pragma unroll
      for (int o = 1; o < 16; o <<= 1) {
        p0 += __shfl_xor(p0, o);
        p1 += __shfl_xor(p1, o);
      }
      if (m16 == 0 && n < N) {
        atomicAdd(&accO[nl][0], p0);
        atomicAdd(&accO[nl][1], p1);
      }
    }
    __syncthreads();
    if (threadIdx.x < NPB * 2) {
      int nl = threadIdx.x >> 1, o = threadIdx.x & 1;
      int n = nb0 + nl;
      if (n < N) out[2 * n + o] = accO[nl][o] + b2[o];
    }
  }
}

extern "C" void kernel_launch(void* const* d_in, const int* in_sizes, int n_in,
                              void* d_out, int out_size, void* d_ws, size_t ws_size,
                              hipStream_t stream) {
  const float* x      = (const float*)d_in[0];
  const int*   ei     = (const int*)d_in[1];
  const int*   et     = (const int*)d_in[2];
  const float* lin1_w = (const float*)d_in[3];
  const float* lin1_b = (const float*)d_in[4];
  const float* bases  = (const float*)d_in[5];
  const float* comp   = (const float*)d_in[6];
  const float* root   = (const float*)d_in[7];
  const float* cbias  = (const float*)d_in[8];
  const float* lin2_w = (const float*)d_in[9];
  const float* lin2_b = (const float*)d_in[10];
  float* out = (float*)d_out;

  int N = in_sizes[0] / HDIM;
  int E = in_sizes[2];
  int M = N * RREL;
  const int* srcp = ei;
  const int* dstp = ei + E;

  char* p = (char*)d_ws;
  auto carve = [&](size_t bytes) { char* r = p; p += (bytes + 255) & ~(size_t)255; return r; };
  ushort* hb_a    = (ushort*)carve((size_t)N * HDIM * 2);
  ushort* hb_b    = (ushort*)carve((size_t)N * HDIM * 2);
  uint*   sorted  = (uint*)carve((size_t)(E + 160) * 4);  // +160: iv preload overrun slack
  uint*   deg8    = (uint*)carve((size_t)M * 4);
  uint*   off8    = (uint*)carve((size_t)(M + 1) * 4);
  uint*   bsum    = (uint*)carve(8192);
  ushort* wt_lin1 = (ushort*)carve((size_t)HDIM * HDIM * 2);
  ushort* wt_conv = (ushort*)carve((size_t)2 * HDIM * KCAT * 2);
  carve((size_t)8 << 20);  // slack (masked-index DMA reads stay in ws)

  hipMemsetAsync(deg8, 0, (size_t)M * 4, stream);

  int eb    = (E + 255) / 256;
  int nwg   = (N + NPB - 1) / NPB;
  int nblk1 = (M + 1023) / 1024;   // <= 1023 (N <= 131072, need nblk1+1 bsum entries)

  k_prep_wt<<<(2 * HDIM * KCAT + 255) / 256, 256, 0, stream>>>(lin1_w, bases, comp, root, wt_lin1, wt_conv);
  k_hist<<<eb, 256, 0, stream>>>(dstp, et, E, deg8);
  k_scan1<<<nblk1, 256, 0, stream>>>(deg8, off8, bsum, M);
  k_scan2<<<1, 1024, 0, stream>>>(bsum, off8, nblk1, M, (uint)E);
  k_scatter<<<eb, 256, 0, stream>>>(srcp, dstp, et, E, off8, bsum, deg8, sorted);

  k_lin1<<<nwg, 256, 0, stream>>>(x, wt_lin1, lin1_b, hb_a, N);
  k_conv<<<nwg, 256, 0, stream>>>(off8, bsum, sorted, hb_a, wt_conv, cbias,
                                  hb_b, N, 0, lin2_w, lin2_b, out);
  k_conv<<<nwg, 256, 0, stream>>>(off8, bsum, sorted, hb_b, wt_conv + HDIM * KCAT,
                                  cbias + HDIM, hb_a, N, 1, lin2_w, lin2_b, out);
}

// Round 11
// 425.867 us; speedup vs baseline: 845.5840x; 845.5840x over previous
//
#include <hip/hip_runtime.h>

// ResRGCN: h=x@W1+b1; 2x {per-(dst,rel) mean aggr -> [h|agg]@[root;W_r]+bias, h+=relu}; out=h@W2+b2
// Layer 3 of the reference is dead (output discarded) and is skipped.
// Edges counting-sorted by key = dst*8+type; each wave's 4 nodes own one flat
// contiguous edge range (33 boundaries). k_conv: 8-slot x 8-edge global_load_lds
// pipeline (depth-7 lookahead, counted vmcnt); lin2 fused into conv-2 epilogue.
// r10 post-mortem: scan3-fold double-counted bsum at the off[M] seam -> corrupted
// eEnd -> runaway serial fallback + readlane wraparound spin (200ms waves).
// Fix: dedicated scan3 restored (exact global off8); OOB boundary lanes = UINT_MAX
// so any stray readlane terminates loops.

#define HDIM 64
#define RREL 8
#define KCAT 576   // 64 (root/self) + 8*64 (relations)
#define NPB  16    // nodes per workgroup in MFMA kernels
#define APAD 584   // padded LDS row
#define CH   8     // edges per batch (1 DMA x 8 rows)
#define SLOTS 8    // pipeline slots per wave

typedef short  short8 __attribute__((ext_vector_type(8)));
typedef __bf16 bf16x8 __attribute__((ext_vector_type(8)));
typedef float  f32x4  __attribute__((ext_vector_type(4)));
typedef unsigned int uint;
typedef unsigned short ushort;

#define GLB(p) ((const __attribute__((address_space(1))) void*)(p))
#define LDS(p) ((__attribute__((address_space(3))) void*)(p))

static __device__ __forceinline__ ushort f2bf(float f) {
  uint u = __builtin_bit_cast(uint, f);
  u += 0x7FFFu + ((u >> 16) & 1u);
  return (ushort)(u >> 16);
}
static __device__ __forceinline__ float bf2f(ushort s) {
  uint u = ((uint)s) << 16;
  return __builtin_bit_cast(float, u);
}

// ---- weight prep: wt_lin1[j][k]=lin1_w[k][j]; wt_conv[l][j][k] = cat(root_l, W_r)^T in bf16
__global__ void k_prep_wt(const float* __restrict__ lin1_w, const float* __restrict__ bases,
                          const float* __restrict__ comp, const float* __restrict__ root,
                          ushort* __restrict__ wt_lin1, ushort* __restrict__ wt_conv) {
  int t = blockIdx.x * 256 + threadIdx.x;
  if (t < HDIM * HDIM) {
    int j = t >> 6, k = t & 63;
    wt_lin1[t] = f2bf(lin1_w[k * HDIM + j]);
  }
  if (t < 2 * HDIM * KCAT) {
    int l = t / (HDIM * KCAT);
    int rem = t - l * (HDIM * KCAT);
    int j = rem / KCAT;
    int k = rem - j * KCAT;
    float v;
    if (k < HDIM) {
      v = root[(l * HDIM + k) * HDIM + j];
    } else {
      int r = (k - HDIM) >> 6;
      int i = (k - HDIM) & 63;
      v = 0.f;
      #pragma unroll
      for (int b = 0; b < 4; ++b)
        v += comp[(l * RREL + r) * 4 + b] * bases[((l * 4 + b) * HDIM + i) * HDIM + j];
    }
    wt_conv[t] = f2bf(v);
  }
}

// ---- build CSR over keys = dst*8 + type (M = 8N bins)
__global__ void k_hist(const int* __restrict__ dst, const int* __restrict__ et, int E,
                       uint* __restrict__ deg) {
  int e = blockIdx.x * 256 + threadIdx.x;
  if (e < E) atomicAdd(&deg[dst[e] * RREL + et[e]], 1u);
}

__global__ void k_scan1(const uint* __restrict__ deg, uint* __restrict__ off,
                        uint* __restrict__ bsum, int M) {
  __shared__ uint s[256];
  int t = threadIdx.x;
  int base = blockIdx.x * 1024 + t * 4;
  uint v0 = 0, v1 = 0, v2 = 0, v3 = 0;
  if (base + 3 < M) {
    uint4 u = *(const uint4*)(deg + base);
    v0 = u.x; v1 = u.y; v2 = u.z; v3 = u.w;
  } else {
    if (base < M)     v0 = deg[base];
    if (base + 1 < M) v1 = deg[base + 1];
    if (base + 2 < M) v2 = deg[base + 2];
    if (base + 3 < M) v3 = deg[base + 3];
  }
  uint tsum = v0 + v1 + v2 + v3;
  s[t] = tsum;
  __syncthreads();
  for (int o = 1; o < 256; o <<= 1) {
    uint u = (t >= o) ? s[t - o] : 0u;
    __syncthreads();
    s[t] += u;
    __syncthreads();
  }
  uint ex = s[t] - tsum;
  if (base < M)     off[base]     = ex;
  if (base + 1 < M) off[base + 1] = ex + v0;
  if (base + 2 < M) off[base + 2] = ex + v0 + v1;
  if (base + 3 < M) off[base + 3] = ex + v0 + v1 + v2;
  if (t == 255) bsum[blockIdx.x] = s[255];
}

__global__ void k_scan2(uint* __restrict__ bsum, uint* __restrict__ off, int nblk, int M, uint E) {
  __shared__ uint s[1024];
  int t = threadIdx.x;
  uint v = (t < nblk) ? bsum[t] : 0u;
  s[t] = v;
  __syncthreads();
  for (int o = 1; o < 1024; o <<= 1) {
    uint u = (t >= o) ? s[t - o] : 0u;
    __syncthreads();
    s[t] += u;
    __syncthreads();
  }
  if (t < nblk) bsum[t] = s[t] - v;
  if (t == 0) off[M] = E;
}

__global__ void k_scan3(uint* __restrict__ off, const uint* __restrict__ bsum, int M) {
  int i = blockIdx.x * 256 + threadIdx.x;
  if (i < M) off[i] += bsum[i >> 10];
}

// counting-sort scatter; atomicSub on deg leaves it zeroed (self-restoring)
__global__ void k_scatter(const int* __restrict__ src, const int* __restrict__ dst,
                          const int* __restrict__ et, int E, const uint* __restrict__ off,
                          uint* __restrict__ deg, uint* __restrict__ sorted) {
  int e = blockIdx.x * 256 + threadIdx.x;
  if (e < E) {
    int key = dst[e] * RREL + et[e];
    uint p = off[key] + atomicSub(&deg[key], 1u) - 1u;
    sorted[p] = (uint)src[e];
  }
}

// ---- lin1: hb = bf16(x @ W1 + b1) (MFMA over K=64)
__global__ void k_lin1(const float* __restrict__ x, const ushort* __restrict__ wt,
                       const float* __restrict__ bias, ushort* __restrict__ hb, int N) {
  __shared__ ushort A[NPB][72];
  int nodebase = blockIdx.x * NPB;
  for (int i = threadIdx.x; i < NPB * HDIM; i += 256) {
    int nl = i >> 6, c = i & 63;
    int n = nodebase + nl;
    A[nl][c] = (n < N) ? f2bf(x[(size_t)n * HDIM + c]) : (ushort)0;
  }
  __syncthreads();
  int lane = threadIdx.x & 63, wid = threadIdx.x >> 6;
  int m16 = lane & 15, khi = lane >> 4;
  int colbase = wid * 16;
  f32x4 acc = {0.f, 0.f, 0.f, 0.f};
  #pragma unroll
  for (int kk = 0; kk < HDIM; kk += 32) {
    int k0 = kk + khi * 8;
    short8 av = *(const short8*)&A[m16][k0];
    short8 bv = *(const short8*)&wt[(colbase + m16) * HDIM + k0];
    acc = __builtin_amdgcn_mfma_f32_16x16x32_bf16(
        __builtin_bit_cast(bf16x8, av), __builtin_bit_cast(bf16x8, bv), acc, 0, 0, 0);
  }
  int j = colbase + m16;
  float bj = bias[j];
  #pragma unroll
  for (int r = 0; r < 4; ++r) {
    int nl = khi * 4 + r;
    int n = nodebase + nl;
    if (n < N) hb[(size_t)n * HDIM + j] = f2bf(acc[r] + bj);
  }
}

// ---- fused RGCN layer: 8-deep DMA pipeline + scalar boundary-flush walk.
//      last!=0: skip hb_out, fuse lin2 (out = h3 @ W2 + b2) in epilogue.
__global__ void __launch_bounds__(256, 3)
k_conv(const uint* __restrict__ off8, const uint* __restrict__ sorted,
       const ushort* __restrict__ hb_in, const ushort* __restrict__ wt,
       const float* __restrict__ bias, ushort* __restrict__ hb_out, int N, int last,
       const float* __restrict__ w2, const float* __restrict__ b2,
       float* __restrict__ out) {
  __shared__ ushort A[NPB][APAD];                            // 18.7 KB
  __shared__ __align__(16) ushort land[4][SLOTS][CH * HDIM]; // 32 KB
  __shared__ float accO[NPB][2];
  int nb0 = blockIdx.x * NPB;
  int lane = threadIdx.x & 63, wid = threadIdx.x >> 6;

  if (threadIdx.x < NPB * 2) accO[threadIdx.x >> 1][threadIdx.x & 1] = 0.f;

  // stage self rows: thread t -> row t>>4, chans (t&15)*4 (one uint2 each)
  {
    int tt = threadIdx.x;
    int nl = tt >> 4, c = (tt & 15) * 4;
    int n = nb0 + nl;
    uint2 v = {0u, 0u};
    if (n < N) v = *(const uint2*)&hb_in[(size_t)n * HDIM + c];
    *(uint2*)&A[nl][c] = v;
  }

  // this wave's 4 nodes: 33 boundaries in lanes 0..32; other lanes = UINT_MAX
  // (any stray readlane -> nextb huge -> loops terminate; r10 lesson)
  int n0 = nb0 + wid * 4;
  uint M8 = (uint)N * RREL;
  uint bidx = (uint)n0 * RREL + (uint)lane;
  uint bl = (bidx > M8) ? M8 : bidx;               // clamp -> empty segs past N
  uint bvv = (lane < 33) ? off8[bl] : 0xFFFFFFFFu;

  uint e0   = (uint)__builtin_amdgcn_readlane((int)bvv, 0);
  uint eEnd = (uint)__builtin_amdgcn_readlane((int)bvv, 32);
  uint tot  = eEnd - e0;
  uint nbat = (tot + CH - 1) / CH;
  uint cap  = nbat > 16u ? 16u : nbat;             // <=128 edges pipelined

  // preload up to 128 edge indices into 2 regs (2 coalesced loads; slack covers overrun)
  uint iv0 = sorted[e0 + (uint)lane];
  uint iv1 = sorted[e0 + 64u + (uint)lane];

  float run = 0.f;
  int ri = 0;
  uint prevb = e0;
  uint nextb = (uint)__builtin_amdgcn_readlane((int)bvv, 1);
  const ushort* hlane = hb_in + lane;

  int r8i = lane >> 3, c8 = lane & 7;
  auto stage = [&](uint t) {                       // addresses from regs -- no VMEM dep
    uint s = t & (SLOTS - 1u);
    int srcv = (int)((t < 8u) ? iv0 : iv1);
    uint q = (t * 8u + (uint)r8i) & 63u;
    uint idx = (uint)__shfl(srcv, (int)q) & 0x1FFFFu;
    const ushort* sA = hb_in + ((size_t)idx << 6) + ((uint)c8 << 3);
    __builtin_amdgcn_global_load_lds(GLB(sA), LDS(&land[wid][s][0]), 16, 0, 0);
  };

  if (cap > 0) {
    // drain all prior vmem so counted waits see only our DMAs
    asm volatile("s_waitcnt vmcnt(0)" ::: "memory");
    __builtin_amdgcn_sched_barrier(0);
    for (uint i = 0; i < 7u && i < cap; ++i) stage(i);
    for (uint t = 0; t < cap; ++t) {
      uint rem = cap - 1u - t;
      if (rem > 6u) rem = 6u;
      switch (rem) {                               // counted wait: batch t landed
        case 6: asm volatile("s_waitcnt vmcnt(6)" ::: "memory"); break;
        case 5: asm volatile("s_waitcnt vmcnt(5)" ::: "memory"); break;
        case 4: asm volatile("s_waitcnt vmcnt(4)" ::: "memory"); break;
        case 3: asm volatile("s_waitcnt vmcnt(3)" ::: "memory"); break;
        case 2: asm volatile("s_waitcnt vmcnt(2)" ::: "memory"); break;
        case 1: asm volatile("s_waitcnt vmcnt(1)" ::: "memory"); break;
        default: asm volatile("s_waitcnt vmcnt(0)" ::: "memory"); break;
      }
      __builtin_amdgcn_sched_barrier(0);
      // read this batch's 8 values for this lane's channel
      float g[CH];
      const ushort* lb = &land[wid][t & (SLOTS - 1u)][lane];
      #pragma unroll
      for (int j = 0; j < CH; ++j) g[j] = bf2f(lb[j * HDIM]);
      if (t + 7u < cap) stage(t + 7u);             // refill consumed slot
      // scalar boundary-flush walk
      uint base = e0 + t * CH;
      uint m = eEnd - base;                        // scalar
      if (m > CH) m = CH;
      #pragma unroll
      for (int j = 0; j < CH; ++j) {
        if ((uint)j < m) {                         // scalar guard
          uint pos = base + (uint)j;
          while (pos >= nextb) {                   // scalar flush walk
            float mean = run * __builtin_amdgcn_rcpf(fmaxf((float)(nextb - prevb), 1.0f));
            int row = (wid << 2) + (ri >> 3);
            A[row][HDIM + (ri & 7) * HDIM + lane] = f2bf(mean);
            run = 0.f;
            ++ri;
            prevb = nextb;
            nextb = (uint)__builtin_amdgcn_readlane((int)bvv, ri + 1);
          }
          run += g[j];
        }
      }
    }
  }
  asm volatile("" ::: "memory");
  // serial fallback for >128-edge waves (P ~ 1e-10, correctness only)
  for (uint e = e0 + cap * (uint)CH; e < eEnd; ++e) {
    uint idx = sorted[e] & 0x1FFFFu;
    float v = bf2f(hlane[(size_t)idx << 6]);
    while (e >= nextb) {
      float mean = run * __builtin_amdgcn_rcpf(fmaxf((float)(nextb - prevb), 1.0f));
      int row = (wid << 2) + (ri >> 3);
      A[row][HDIM + (ri & 7) * HDIM + lane] = f2bf(mean);
      run = 0.f;
      ++ri;
      prevb = nextb;
      nextb = (uint)__builtin_amdgcn_readlane((int)bvv, ri + 1);
    }
    run += v;
  }
  while (ri < 32) {                                // trailing flushes (incl. empty)
    float mean = run * __builtin_amdgcn_rcpf(fmaxf((float)(nextb - prevb), 1.0f));
    int row = (wid << 2) + (ri >> 3);
    A[row][HDIM + (ri & 7) * HDIM + lane] = f2bf(mean);
    run = 0.f;
    ++ri;
    prevb = nextb;
    if (ri < 32) nextb = (uint)__builtin_amdgcn_readlane((int)bvv, ri + 1);
  }
  __syncthreads();

  // MFMA: [16 x 576] @ [576 x 64]
  int m16 = lane & 15, khi = lane >> 4;
  int colbase = wid * 16;
  f32x4 acc = {0.f, 0.f, 0.f, 0.f};
  #pragma unroll
  for (int kk = 0; kk < KCAT; kk += 32) {
    int k0 = kk + khi * 8;
    short8 av = *(const short8*)&A[m16][k0];
    short8 bv = *(const short8*)&wt[(uint)(colbase + m16) * KCAT + k0];
    acc = __builtin_amdgcn_mfma_f32_16x16x32_bf16(
        __builtin_bit_cast(bf16x8, av), __builtin_bit_cast(bf16x8, bv), acc, 0, 0, 0);
  }
  int j = colbase + m16;
  float bj = bias[j];
  if (!last) {
    #pragma unroll
    for (int r = 0; r < 4; ++r) {
      int nl = khi * 4 + r;
      int n = nb0 + nl;
      if (n < N) {
        float hs = bf2f(A[nl][j]);                 // self row (residual base)
        float hn = hs + fmaxf(acc[r] + bj, 0.f);
        hb_out[(uint)n * HDIM + j] = f2bf(hn);
      }
    }
  } else {
    // fused lin2: out[n] = h3[n] @ W2 + b2 (shfl-reduce over 16 col-lanes, LDS combine)
    float w0 = w2[j * 2], w1 = w2[j * 2 + 1];
    #pragma unroll
    for (int r = 0; r < 4; ++r) {
      int nl = khi * 4 + r;
      int n = nb0 + nl;
      float hn = 0.f;
      if (n < N) {
        float hs = bf2f(A[nl][j]);
        hn = hs + fmaxf(acc[r] + bj, 0.f);
      }
      float p0 = hn * w0, p1 = hn * w1;
      #pragma unroll
      for (int o = 1; o < 16; o <<= 1) {
        p0 += __shfl_xor(p0, o);
        p1 += __shfl_xor(p1, o);
      }
      if (m16 == 0 && n < N) {
        atomicAdd(&accO[nl][0], p0);
        atomicAdd(&accO[nl][1], p1);
      }
    }
    __syncthreads();
    if (threadIdx.x < NPB * 2) {
      int nl = threadIdx.x >> 1, o = threadIdx.x & 1;
      int n = nb0 + nl;
      if (n < N) out[2 * n + o] = accO[nl][o] + b2[o];
    }
  }
}

extern "C" void kernel_launch(void* const* d_in, const int* in_sizes, int n_in,
                              void* d_out, int out_size, void* d_ws, size_t ws_size,
                              hipStream_t stream) {
  const float* x      = (const float*)d_in[0];
  const int*   ei     = (const int*)d_in[1];
  const int*   et     = (const int*)d_in[2];
  const float* lin1_w = (const float*)d_in[3];
  const float* lin1_b = (const float*)d_in[4];
  const float* bases  = (const float*)d_in[5];
  const float* comp   = (const float*)d_in[6];
  const float* root   = (const float*)d_in[7];
  const float* cbias  = (const float*)d_in[8];
  const float* lin2_w = (const float*)d_in[9];
  const float* lin2_b = (const float*)d_in[10];
  float* out = (float*)d_out;

  int N = in_sizes[0] / HDIM;
  int E = in_sizes[2];
  int M = N * RREL;
  const int* srcp = ei;
  const int* dstp = ei + E;

  char* p = (char*)d_ws;
  auto carve = [&](size_t bytes) { char* r = p; p += (bytes + 255) & ~(size_t)255; return r; };
  ushort* hb_a    = (ushort*)carve((size_t)N * HDIM * 2);
  ushort* hb_b    = (ushort*)carve((size_t)N * HDIM * 2);
  uint*   sorted  = (uint*)carve((size_t)(E + 160) * 4);  // +160: iv preload overrun slack
  uint*   deg8    = (uint*)carve((size_t)M * 4);
  uint*   off8    = (uint*)carve((size_t)(M + 1) * 4);
  uint*   bsum    = (uint*)carve(8192);
  ushort* wt_lin1 = (ushort*)carve((size_t)HDIM * HDIM * 2);
  ushort* wt_conv = (ushort*)carve((size_t)2 * HDIM * KCAT * 2);
  carve((size_t)8 << 20);  // slack (masked-index DMA reads stay in ws)

  hipMemsetAsync(deg8, 0, (size_t)M * 4, stream);

  int eb    = (E + 255) / 256;
  int nwg   = (N + NPB - 1) / NPB;
  int nblk1 = (M + 1023) / 1024;   // <= 1024 (N <= 131072)
  int mb    = (M + 255) / 256;

  k_prep_wt<<<(2 * HDIM * KCAT + 255) / 256, 256, 0, stream>>>(lin1_w, bases, comp, root, wt_lin1, wt_conv);
  k_hist<<<eb, 256, 0, stream>>>(dstp, et, E, deg8);
  k_scan1<<<nblk1, 256, 0, stream>>>(deg8, off8, bsum, M);
  k_scan2<<<1, 1024, 0, stream>>>(bsum, off8, nblk1, M, (uint)E);
  k_scan3<<<mb, 256, 0, stream>>>(off8, bsum, M);
  k_scatter<<<eb, 256, 0, stream>>>(srcp, dstp, et, E, off8, deg8, sorted);

  k_lin1<<<nwg, 256, 0, stream>>>(x, wt_lin1, lin1_b, hb_a, N);
  k_conv<<<nwg, 256, 0, stream>>>(off8, sorted, hb_a, wt_conv, cbias,
                                  hb_b, N, 0, lin2_w, lin2_b, out);
  k_conv<<<nwg, 256, 0, stream>>>(off8, sorted, hb_b, wt_conv + HDIM * KCAT,
                                  cbias + HDIM, hb_a, N, 1, lin2_w, lin2_b, out);
}

// Round 12
// 321.078 us; speedup vs baseline: 1121.5526x; 1.3264x over previous
//
#include <hip/hip_runtime.h>

// ResRGCN: h=x@W1+b1; 2x {per-(dst,rel) mean aggr -> basis-space GEMM + residual}; out=h@W2+b2
// Layer 3 of the reference is dead (output discarded) and is skipped.
// out_conv = [h | z0..z3] @ [root; B_0..B_3] + bias, where z_b = sum_r comp[r,b]*mean_r
// (z accumulated in VGPRs during the flush walk -> A-tile is 320 wide, not 576).
// Edges counting-sorted by key = dst*8+type. Conv engine = r6's proven chunk-16
// readfirstlane SGPR-base gather walk (best measured: 101us, 8 blocks/CU).
// Random-gather service wall ~19cy/line/CU confirmed across 6 designs (r5-r11);
// this round harvests LDS/MFMA/dispatch/fusion savings around it.
// scan3 folded into users via off8[i]+bsum[i>>10]; scan2 writes the off[M] seam
// as E - bsum_excl[M>>10] (r10 bug fixed); lin2 fused into conv-2 epilogue.

#define HDIM 64
#define RREL 8
#define NB   4     // bases
#define KC2  320   // 64 (self) + 4*64 (basis)
#define NPB  16    // nodes per workgroup
#define APAD 328   // padded LDS row (rows offset 4 banks -> 2-way, free)

typedef short  short8 __attribute__((ext_vector_type(8)));
typedef __bf16 bf16x8 __attribute__((ext_vector_type(8)));
typedef float  f32x4  __attribute__((ext_vector_type(4)));
typedef unsigned int uint;
typedef unsigned short ushort;

static __device__ __forceinline__ ushort f2bf(float f) {
  uint u = __builtin_bit_cast(uint, f);
  u += 0x7FFFu + ((u >> 16) & 1u);
  return (ushort)(u >> 16);
}
static __device__ __forceinline__ float bf2f(ushort s) {
  uint u = ((uint)s) << 16;
  return __builtin_bit_cast(float, u);
}

// ---- weight prep: wt_lin1[j][k]=lin1_w[k][j]; wt_conv[l][j][k] = cat(root_l, B_0..B_3)^T
__global__ void k_prep_wt(const float* __restrict__ lin1_w, const float* __restrict__ bases,
                          const float* __restrict__ root,
                          ushort* __restrict__ wt_lin1, ushort* __restrict__ wt_conv) {
  int t = blockIdx.x * 256 + threadIdx.x;
  if (t < HDIM * HDIM) {
    int j = t >> 6, k = t & 63;
    wt_lin1[t] = f2bf(lin1_w[k * HDIM + j]);
  }
  if (t < 2 * HDIM * KC2) {
    int l = t / (HDIM * KC2);
    int rem = t - l * (HDIM * KC2);
    int j = rem / KC2;
    int k = rem - j * KC2;
    float v;
    if (k < HDIM) {
      v = root[(l * HDIM + k) * HDIM + j];
    } else {
      int b = (k - HDIM) >> 6;
      int i = (k - HDIM) & 63;
      v = bases[((l * NB + b) * HDIM + i) * HDIM + j];
    }
    wt_conv[t] = f2bf(v);
  }
}

// ---- build CSR over keys = dst*8 + type (M = 8N bins)
__global__ void k_hist(const int* __restrict__ dst, const int* __restrict__ et, int E,
                       uint* __restrict__ deg) {
  int e = blockIdx.x * 256 + threadIdx.x;
  if (e < E) atomicAdd(&deg[dst[e] * RREL + et[e]], 1u);
}

__global__ void k_scan1(const uint* __restrict__ deg, uint* __restrict__ off,
                        uint* __restrict__ bsum, int M) {
  __shared__ uint s[256];
  int t = threadIdx.x;
  int base = blockIdx.x * 1024 + t * 4;
  uint v0 = 0, v1 = 0, v2 = 0, v3 = 0;
  if (base + 3 < M) {
    uint4 u = *(const uint4*)(deg + base);
    v0 = u.x; v1 = u.y; v2 = u.z; v3 = u.w;
  } else {
    if (base < M)     v0 = deg[base];
    if (base + 1 < M) v1 = deg[base + 1];
    if (base + 2 < M) v2 = deg[base + 2];
    if (base + 3 < M) v3 = deg[base + 3];
  }
  uint tsum = v0 + v1 + v2 + v3;
  s[t] = tsum;
  __syncthreads();
  for (int o = 1; o < 256; o <<= 1) {
    uint u = (t >= o) ? s[t - o] : 0u;
    __syncthreads();
    s[t] += u;
    __syncthreads();
  }
  uint ex = s[t] - tsum;
  if (base < M)     off[base]     = ex;
  if (base + 1 < M) off[base + 1] = ex + v0;
  if (base + 2 < M) off[base + 2] = ex + v0 + v1;
  if (base + 3 < M) off[base + 3] = ex + v0 + v1 + v2;
  if (t == 255) bsum[blockIdx.x] = s[255];
}

// scan2: exclusive-scan block sums; write the off[M] seam so that
// off[i] + bsum[i>>10] is the exact global offset for ALL i in [0, M].
__global__ void k_scan2(uint* __restrict__ bsum, uint* __restrict__ off, int nblk, int M, uint E) {
  __shared__ uint s[1024];
  int t = threadIdx.x;
  uint v = (t < nblk) ? bsum[t] : 0u;
  s[t] = v;
  __syncthreads();
  for (int o = 1; o < 1024; o <<= 1) {
    uint u = (t >= o) ? s[t - o] : 0u;
    __syncthreads();
    s[t] += u;
    __syncthreads();
  }
  uint ex = s[t] - v;
  if (t < nblk) bsum[t] = ex;
  if (t == nblk - 1) bsum[nblk] = s[t];          // inclusive total (= E)
  int q = M >> 10;
  if (t == q && t < nblk) off[M] = E - ex;       // seam: off[M]+bsum[q] == E
  if (q == nblk && t == 0) off[M] = 0;
}

// counting-sort scatter; atomicSub on deg leaves it zeroed (self-restoring)
__global__ void k_scatter(const int* __restrict__ src, const int* __restrict__ dst,
                          const int* __restrict__ et, int E, const uint* __restrict__ off,
                          const uint* __restrict__ bsum, uint* __restrict__ deg,
                          uint* __restrict__ sorted) {
  int e = blockIdx.x * 256 + threadIdx.x;
  if (e < E) {
    int key = dst[e] * RREL + et[e];
    uint p = off[key] + bsum[key >> 10] + atomicSub(&deg[key], 1u) - 1u;
    sorted[p] = (uint)src[e];
  }
}

// ---- lin1: hb = bf16(x @ W1 + b1) (MFMA over K=64), float4 input loads
__global__ void k_lin1(const float* __restrict__ x, const ushort* __restrict__ wt,
                       const float* __restrict__ bias, ushort* __restrict__ hb, int N) {
  __shared__ ushort A[NPB][72];
  int nodebase = blockIdx.x * NPB;
  {
    int t = threadIdx.x;
    int nl = t >> 4, c = (t & 15) * 4;
    int n = nodebase + nl;
    ushort4 o = {0, 0, 0, 0};
    if (n < N) {
      f32x4 v = *(const f32x4*)&x[(size_t)n * HDIM + c];
      o.x = f2bf(v[0]); o.y = f2bf(v[1]); o.z = f2bf(v[2]); o.w = f2bf(v[3]);
    }
    *(ushort4*)&A[nl][c] = o;
  }
  __syncthreads();
  int lane = threadIdx.x & 63, wid = threadIdx.x >> 6;
  int m16 = lane & 15, khi = lane >> 4;
  int colbase = wid * 16;
  f32x4 acc = {0.f, 0.f, 0.f, 0.f};
  #pragma unroll
  for (int kk = 0; kk < HDIM; kk += 32) {
    int k0 = kk + khi * 8;
    short8 av = *(const short8*)&A[m16][k0];
    short8 bv = *(const short8*)&wt[(colbase + m16) * HDIM + k0];
    acc = __builtin_amdgcn_mfma_f32_16x16x32_bf16(
        __builtin_bit_cast(bf16x8, av), __builtin_bit_cast(bf16x8, bv), acc, 0, 0, 0);
  }
  int j = colbase + m16;
  float bj = bias[j];
  #pragma unroll
  for (int r = 0; r < 4; ++r) {
    int nl = khi * 4 + r;
    int n = nodebase + nl;
    if (n < N) hb[(size_t)n * HDIM + j] = f2bf(acc[r] + bj);
  }
}

// ---- fused RGCN layer: r6 chunk-16 gather walk, z-basis accumulation in VGPRs,
//      MFMA [16x320]@[320x64]; last!=0 fuses lin2 and skips hb_out.
__global__ void __launch_bounds__(256, 6)
k_conv(const uint* __restrict__ off8, const uint* __restrict__ bsum,
       const uint* __restrict__ sorted, const ushort* __restrict__ hb_in,
       const float* __restrict__ compL, const ushort* __restrict__ wt,
       const float* __restrict__ bias, ushort* __restrict__ hb_out, int N, int last,
       const float* __restrict__ w2, const float* __restrict__ b2,
       float* __restrict__ out) {
  __shared__ ushort A[NPB][APAD];     // 10.5 KB
  __shared__ float  cmp[RREL * NB];   // comp for this layer
  __shared__ float  accO[NPB][2];
  int nb0 = blockIdx.x * NPB;
  int lane = threadIdx.x & 63, wid = threadIdx.x >> 6;

  if (threadIdx.x < RREL * NB) cmp[threadIdx.x] = compL[threadIdx.x];
  if (threadIdx.x < NPB * 2) accO[threadIdx.x >> 1][threadIdx.x & 1] = 0.f;
  {
    int t = threadIdx.x;
    int nl = t >> 4, c = (t & 15) * 4;
    int n = nb0 + nl;
    uint2 v = {0u, 0u};
    if (n < N) v = *(const uint2*)&hb_in[(size_t)n * HDIM + c];
    *(uint2*)&A[nl][c] = v;
  }
  __syncthreads();

  const ushort* hlane = hb_in + lane;
  for (int q = 0; q < 4; ++q) {
    int nl = wid * 4 + q;
    int n = nb0 + nl;
    if (n < N) {
      // boundaries: lanes 0..8 hold global offsets (scan3 folded); others UINT_MAX
      uint bv = 0xFFFFFFFFu;
      if (lane < 9) {
        uint bl = (uint)n * RREL + (uint)lane;
        bv = off8[bl] + bsum[bl >> 10];
      }
      uint s0 = (uint)__builtin_amdgcn_readlane((int)bv, 0);
      uint s1 = (uint)__builtin_amdgcn_readlane((int)bv, 8);
      float run = 0.f, z0 = 0.f, z1 = 0.f, z2 = 0.f, z3 = 0.f;
      int rel = 0;
      uint prevb = s0;
      uint nextb = (uint)__builtin_amdgcn_readlane((int)bv, 1);
      for (uint base = s0; base < s1; base += 16u) {
        // 16 index words via uniform loads (may overrun segment; slack covers)
        const uint* sp = sorted + base;
        uint4 w0 = *(const uint4*)(sp);
        uint4 w1 = *(const uint4*)(sp + 4);
        uint4 w2v = *(const uint4*)(sp + 8);
        uint4 w3 = *(const uint4*)(sp + 12);
        uint idx[16] = {w0.x, w0.y, w0.z, w0.w, w1.x, w1.y, w1.z, w1.w,
                        w2v.x, w2v.y, w2v.z, w2v.w, w3.x, w3.y, w3.z, w3.w};
        float g[16];
        #pragma unroll
        for (int j = 0; j < 16; ++j) {
          uint ij = (uint)__builtin_amdgcn_readfirstlane((int)idx[j]) & 0x1FFFFu;
          g[j] = bf2f(hlane[(size_t)ij << 6]);    // SGPR base + lane*2 voffset
        }
        uint m = s1 - base;                        // scalar
        #pragma unroll
        for (int j = 0; j < 16; ++j) {
          if ((uint)j < m) {                       // scalar guard
            uint pos = base + (uint)j;
            while (pos >= nextb) {                 // scalar flush walk -> z accum
              float mean = run * __builtin_amdgcn_rcpf(fmaxf((float)(nextb - prevb), 1.0f));
              f32x4 c4 = *(const f32x4*)&cmp[rel * NB];
              z0 += c4[0] * mean; z1 += c4[1] * mean;
              z2 += c4[2] * mean; z3 += c4[3] * mean;
              run = 0.f;
              ++rel;
              prevb = nextb;
              nextb = (uint)__builtin_amdgcn_readlane((int)bv, rel + 1);
            }
            run += g[j];
          }
        }
      }
      while (rel < RREL) {                         // trailing flushes
        float mean = run * __builtin_amdgcn_rcpf(fmaxf((float)(nextb - prevb), 1.0f));
        f32x4 c4 = *(const f32x4*)&cmp[rel * NB];
        z0 += c4[0] * mean; z1 += c4[1] * mean;
        z2 += c4[2] * mean; z3 += c4[3] * mean;
        run = 0.f;
        ++rel;
        prevb = nextb;
        if (rel < RREL)
          nextb = (uint)__builtin_amdgcn_readlane((int)bv, rel + 1);
      }
      A[nl][HDIM + 0 * HDIM + lane] = f2bf(z0);
      A[nl][HDIM + 1 * HDIM + lane] = f2bf(z1);
      A[nl][HDIM + 2 * HDIM + lane] = f2bf(z2);
      A[nl][HDIM + 3 * HDIM + lane] = f2bf(z3);
    } else {
      #pragma unroll
      for (int b = 0; b < NB; ++b) A[nl][HDIM + b * HDIM + lane] = 0;
    }
  }
  __syncthreads();

  // MFMA: [16 x 320] @ [320 x 64]
  int m16 = lane & 15, khi = lane >> 4;
  int colbase = wid * 16;
  f32x4 acc = {0.f, 0.f, 0.f, 0.f};
  #pragma unroll
  for (int kk = 0; kk < KC2; kk += 32) {
    int k0 = kk + khi * 8;
    short8 av = *(const short8*)&A[m16][k0];
    short8 bv = *(const short8*)&wt[(uint)(colbase + m16) * KC2 + k0];
    acc = __builtin_amdgcn_mfma_f32_16x16x32_bf16(
        __builtin_bit_cast(bf16x8, av), __builtin_bit_cast(bf16x8, bv), acc, 0, 0, 0);
  }
  int j = colbase + m16;
  float bj = bias[j];
  if (!last) {
    #pragma unroll
    for (int r = 0; r < 4; ++r) {
      int nl = khi * 4 + r;
      int n = nb0 + nl;
      if (n < N) {
        float hs = bf2f(A[nl][j]);                 // self row (residual base)
        float hn = hs + fmaxf(acc[r] + bj, 0.f);
        hb_out[(uint)n * HDIM + j] = f2bf(hn);
      }
    }
  } else {
    // fused lin2: out[n] = h3[n] @ W2 + b2 (shfl-reduce over 16 col-lanes, LDS combine)
    float w0 = w2[j * 2], w1 = w2[j * 2 + 1];
    #pragma unroll
    for (int r = 0; r < 4; ++r) {
      int nl = khi * 4 + r;
      int n = nb0 + nl;
      float hn = 0.f;
      if (n < N) {
        float hs = bf2f(A[nl][j]);
        hn = hs + fmaxf(acc[r] + bj, 0.f);
      }
      float p0 = hn * w0, p1 = hn * w1;
      #pragma unroll
      for (int o = 1; o < 16; o <<= 1) {
        p0 += __shfl_xor(p0, o);
        p1 += __shfl_xor(p1, o);
      }
      if (m16 == 0 && n < N) {
        atomicAdd(&accO[nl][0], p0);
        atomicAdd(&accO[nl][1], p1);
      }
    }
    __syncthreads();
    if (threadIdx.x < NPB * 2) {
      int nl = threadIdx.x >> 1, o = threadIdx.x & 1;
      int n = nb0 + nl;
      if (n < N) out[2 * n + o] = accO[nl][o] + b2[o];
    }
  }
}

extern "C" void kernel_launch(void* const* d_in, const int* in_sizes, int n_in,
                              void* d_out, int out_size, void* d_ws, size_t ws_size,
                              hipStream_t stream) {
  const float* x      = (const float*)d_in[0];
  const int*   ei     = (const int*)d_in[1];
  const int*   et     = (const int*)d_in[2];
  const float* lin1_w = (const float*)d_in[3];
  const float* lin1_b = (const float*)d_in[4];
  const float* bases  = (const float*)d_in[5];
  const float* comp   = (const float*)d_in[6];
  const float* root   = (const float*)d_in[7];
  const float* cbias  = (const float*)d_in[8];
  const float* lin2_w = (const float*)d_in[9];
  const float* lin2_b = (const float*)d_in[10];
  float* out = (float*)d_out;

  int N = in_sizes[0] / HDIM;
  int E = in_sizes[2];
  int M = N * RREL;
  const int* srcp = ei;
  const int* dstp = ei + E;

  char* p = (char*)d_ws;
  auto carve = [&](size_t bytes) { char* r = p; p += (bytes + 255) & ~(size_t)255; return r; };
  ushort* hb_a    = (ushort*)carve((size_t)N * HDIM * 2);
  ushort* hb_b    = (ushort*)carve((size_t)N * HDIM * 2);
  uint*   sorted  = (uint*)carve((size_t)(E + 160) * 4);  // +160: chunk/preload overrun slack
  uint*   deg8    = (uint*)carve((size_t)M * 4);
  uint*   off8    = (uint*)carve((size_t)(M + 1) * 4);
  uint*   bsum    = (uint*)carve(8192);
  ushort* wt_lin1 = (ushort*)carve((size_t)HDIM * HDIM * 2);
  ushort* wt_conv = (ushort*)carve((size_t)2 * HDIM * KC2 * 2);
  carve((size_t)8 << 20);  // slack (masked-index gathers stay in ws)

  hipMemsetAsync(deg8, 0, (size_t)M * 4, stream);

  int eb    = (E + 255) / 256;
  int nwg   = (N + NPB - 1) / NPB;
  int nblk1 = (M + 1023) / 1024;   // <= 1023 (bsum needs nblk1+1 entries)

  k_prep_wt<<<(2 * HDIM * KC2 + 255) / 256, 256, 0, stream>>>(lin1_w, bases, root, wt_lin1, wt_conv);
  k_hist<<<eb, 256, 0, stream>>>(dstp, et, E, deg8);
  k_scan1<<<nblk1, 256, 0, stream>>>(deg8, off8, bsum, M);
  k_scan2<<<1, 1024, 0, stream>>>(bsum, off8, nblk1, M, (uint)E);
  k_scatter<<<eb, 256, 0, stream>>>(srcp, dstp, et, E, off8, bsum, deg8, sorted);

  k_lin1<<<nwg, 256, 0, stream>>>(x, wt_lin1, lin1_b, hb_a, N);
  k_conv<<<nwg, 256, 0, stream>>>(off8, bsum, sorted, hb_a, comp, wt_conv, cbias,
                                  hb_b, N, 0, lin2_w, lin2_b, out);
  k_conv<<<nwg, 256, 0, stream>>>(off8, bsum, sorted, hb_b, comp + RREL * NB,
                                  wt_conv + HDIM * KC2, cbias + HDIM, hb_a, N, 1,
                                  lin2_w, lin2_b, out);
}

// Round 13
// 248.997 us; speedup vs baseline: 1446.2297x; 1.2895x over previous
//
#include <hip/hip_runtime.h>

// ResRGCN: h=x@W1+b1; 2x {per-(dst,rel) mean aggr -> basis-space GEMM + residual}; out=h@W2+b2
// Layer 3 of the reference is dead (output discarded) and is skipped.
// out_conv = [h | z0..z3] @ [root; B_0..B_3] + bias, z_b = sum_r comp[r,b]*mean_r.
// Edge sort rewritten as 2-level LDS-binned radix (r12 post-mortem: atomic scatter
// had 16x write amplification, 105MB for 6.4MB payload):
//   A) coarse LDS hist (key>>10, 1024 buckets)  B) scan -> offsets+cursors
//   C) coarse scatter in ~64B runs to tmp       D) per-bucket fine sort in LDS,
//      writes off8 directly (replaces scan1/2/3 and deg8).
// Conv engine = r6/r12 chunk-16 readfirstlane SGPR-base gather walk (83us, wall).

#define HDIM 64
#define RREL 8
#define NB   4     // bases
#define KC2  320   // 64 (self) + 4*64 (basis)
#define NPB  16    // nodes per workgroup
#define APAD 328   // padded LDS row

typedef short  short8 __attribute__((ext_vector_type(8)));
typedef __bf16 bf16x8 __attribute__((ext_vector_type(8)));
typedef float  f32x4  __attribute__((ext_vector_type(4)));
typedef unsigned int uint;
typedef unsigned short ushort;

static __device__ __forceinline__ ushort f2bf(float f) {
  uint u = __builtin_bit_cast(uint, f);
  u += 0x7FFFu + ((u >> 16) & 1u);
  return (ushort)(u >> 16);
}
static __device__ __forceinline__ float bf2f(ushort s) {
  uint u = ((uint)s) << 16;
  return __builtin_bit_cast(float, u);
}

// ---- weight prep: wt_lin1[j][k]=lin1_w[k][j]; wt_conv[l][j][k] = cat(root_l, B_0..B_3)^T
__global__ void k_prep_wt(const float* __restrict__ lin1_w, const float* __restrict__ bases,
                          const float* __restrict__ root,
                          ushort* __restrict__ wt_lin1, ushort* __restrict__ wt_conv) {
  int t = blockIdx.x * 256 + threadIdx.x;
  if (t < HDIM * HDIM) {
    int j = t >> 6, k = t & 63;
    wt_lin1[t] = f2bf(lin1_w[k * HDIM + j]);
  }
  if (t < 2 * HDIM * KC2) {
    int l = t / (HDIM * KC2);
    int rem = t - l * (HDIM * KC2);
    int j = rem / KC2;
    int k = rem - j * KC2;
    float v;
    if (k < HDIM) {
      v = root[(l * HDIM + k) * HDIM + j];
    } else {
      int b = (k - HDIM) >> 6;
      int i = (k - HDIM) & 63;
      v = bases[((l * NB + b) * HDIM + i) * HDIM + j];
    }
    wt_conv[t] = f2bf(v);
  }
}

// ---- A) coarse histogram: bucket = (dst*8+et) >> 10, LDS-staged
__global__ void k_chist(const int* __restrict__ dst, const int* __restrict__ et, int E,
                        uint* __restrict__ bcnt) {
  __shared__ uint cnt[1024];
  int t = threadIdx.x;
  for (int i = t; i < 1024; i += 256) cnt[i] = 0;
  __syncthreads();
  int per = (E + gridDim.x - 1) / gridDim.x;
  int e0 = blockIdx.x * per;
  int e1 = e0 + per; if (e1 > E) e1 = E;
  for (int e = e0 + t; e < e1; e += 256)
    atomicAdd(&cnt[((uint)dst[e] * RREL + (uint)et[e]) >> 10], 1u);
  __syncthreads();
  for (int i = t; i < 1024; i += 256)
    if (cnt[i]) atomicAdd(&bcnt[i], cnt[i]);
}

// ---- B) scan bucket counts -> offsets + cursors; write off8 seam
__global__ void k_scanB(const uint* __restrict__ bcnt, uint* __restrict__ boff,
                        uint* __restrict__ gcur, uint* __restrict__ off8,
                        int NBK, uint M8, uint E) {
  __shared__ uint s[1024];
  int t = threadIdx.x;
  uint v = (t < NBK) ? bcnt[t] : 0u;
  s[t] = v;
  __syncthreads();
  for (int o = 1; o < 1024; o <<= 1) {
    uint u = (t >= o) ? s[t - o] : 0u;
    __syncthreads();
    s[t] += u;
    __syncthreads();
  }
  uint ex = s[t] - v;
  if (t < NBK) { boff[t] = ex; gcur[t] = ex; }
  if (t == NBK - 1) boff[NBK] = s[t];
  if (t == 0) off8[M8] = E;
}

// ---- C) coarse scatter: LDS count -> one reservation per (WG,bucket) -> ~64B runs
__global__ void k_cscat(const int* __restrict__ src, const int* __restrict__ dst,
                        const int* __restrict__ et, int E, uint* __restrict__ gcur,
                        uint* __restrict__ tmp) {
  __shared__ uint cnt[1024];
  __shared__ uint base[1024];
  int t = threadIdx.x;
  int per = (E + gridDim.x - 1) / gridDim.x;
  int e0 = blockIdx.x * per;
  int e1 = e0 + per; if (e1 > E) e1 = E;
  for (int i = t; i < 1024; i += 256) cnt[i] = 0;
  __syncthreads();
  for (int e = e0 + t; e < e1; e += 256) {
    uint key = (uint)dst[e] * RREL + (uint)et[e];
    atomicAdd(&cnt[key >> 10], 1u);
  }
  __syncthreads();
  for (int i = t; i < 1024; i += 256) {
    uint c = cnt[i];
    base[i] = c ? atomicAdd(&gcur[i], c) : 0u;
  }
  __syncthreads();
  for (int i = t; i < 1024; i += 256) cnt[i] = 0;
  __syncthreads();
  for (int e = e0 + t; e < e1; e += 256) {
    uint key = (uint)dst[e] * RREL + (uint)et[e];
    uint b = key >> 10;
    uint pos = base[b] + atomicAdd(&cnt[b], 1u);
    tmp[pos] = (uint)src[e] | ((key & 1023u) << 17);   // src(17b) | finekey(10b)
  }
}

// ---- D) fine sort within bucket (1024 fine keys in LDS); writes off8 directly
__global__ void k_fsort(const uint* __restrict__ boff, const uint* __restrict__ tmp,
                        uint* __restrict__ sorted, uint* __restrict__ off8, uint M8) {
  __shared__ uint c2[1024];
  __shared__ uint ex[1024];
  __shared__ uint s[256];
  int t = threadIdx.x;
  uint b = blockIdx.x;
  uint bo = boff[b], be = boff[b + 1];
  for (int i = t; i < 1024; i += 256) c2[i] = 0;
  __syncthreads();
  for (uint i = bo + t; i < be; i += 256) atomicAdd(&c2[tmp[i] >> 17], 1u);
  __syncthreads();
  // 1024-entry exclusive scan, 4 per thread
  int k4 = t * 4;
  uint v0 = c2[k4], v1 = c2[k4 + 1], v2 = c2[k4 + 2], v3 = c2[k4 + 3];
  uint tsum = v0 + v1 + v2 + v3;
  s[t] = tsum;
  __syncthreads();
  for (int o = 1; o < 256; o <<= 1) {
    uint u = (t >= o) ? s[t - o] : 0u;
    __syncthreads();
    s[t] += u;
    __syncthreads();
  }
  uint e0x = s[t] - tsum;
  ex[k4]     = e0x;
  ex[k4 + 1] = e0x + v0;
  ex[k4 + 2] = e0x + v0 + v1;
  ex[k4 + 3] = e0x + v0 + v1 + v2;
  __syncthreads();
  uint gbase = b << 10;
  #pragma unroll
  for (int u = 0; u < 4; ++u) {
    uint g = gbase + (uint)(k4 + u);
    if (g < M8) off8[g] = bo + ex[k4 + u];
  }
  for (int i = t; i < 1024; i += 256) c2[i] = 0;   // reuse as cursors
  __syncthreads();
  for (uint i = bo + t; i < be; i += 256) {
    uint w = tmp[i];
    uint fk = w >> 17;
    uint pos = bo + ex[fk] + atomicAdd(&c2[fk], 1u);
    sorted[pos] = w & 0x1FFFFu;
  }
}

// ---- lin1: hb = bf16(x @ W1 + b1) (MFMA over K=64), float4 input loads
__global__ void k_lin1(const float* __restrict__ x, const ushort* __restrict__ wt,
                       const float* __restrict__ bias, ushort* __restrict__ hb, int N) {
  __shared__ ushort A[NPB][72];
  int nodebase = blockIdx.x * NPB;
  {
    int t = threadIdx.x;
    int nl = t >> 4, c = (t & 15) * 4;
    int n = nodebase + nl;
    ushort4 o = {0, 0, 0, 0};
    if (n < N) {
      f32x4 v = *(const f32x4*)&x[(size_t)n * HDIM + c];
      o.x = f2bf(v[0]); o.y = f2bf(v[1]); o.z = f2bf(v[2]); o.w = f2bf(v[3]);
    }
    *(ushort4*)&A[nl][c] = o;
  }
  __syncthreads();
  int lane = threadIdx.x & 63, wid = threadIdx.x >> 6;
  int m16 = lane & 15, khi = lane >> 4;
  int colbase = wid * 16;
  f32x4 acc = {0.f, 0.f, 0.f, 0.f};
  #pragma unroll
  for (int kk = 0; kk < HDIM; kk += 32) {
    int k0 = kk + khi * 8;
    short8 av = *(const short8*)&A[m16][k0];
    short8 bv = *(const short8*)&wt[(colbase + m16) * HDIM + k0];
    acc = __builtin_amdgcn_mfma_f32_16x16x32_bf16(
        __builtin_bit_cast(bf16x8, av), __builtin_bit_cast(bf16x8, bv), acc, 0, 0, 0);
  }
  int j = colbase + m16;
  float bj = bias[j];
  #pragma unroll
  for (int r = 0; r < 4; ++r) {
    int nl = khi * 4 + r;
    int n = nodebase + nl;
    if (n < N) hb[(size_t)n * HDIM + j] = f2bf(acc[r] + bj);
  }
}

// ---- fused RGCN layer: chunk-16 gather walk, z-basis accumulation in VGPRs,
//      MFMA [16x320]@[320x64]; last!=0 fuses lin2 and skips hb_out.
__global__ void __launch_bounds__(256, 6)
k_conv(const uint* __restrict__ off8, const uint* __restrict__ sorted,
       const ushort* __restrict__ hb_in, const float* __restrict__ compL,
       const ushort* __restrict__ wt, const float* __restrict__ bias,
       ushort* __restrict__ hb_out, int N, int last,
       const float* __restrict__ w2, const float* __restrict__ b2,
       float* __restrict__ out) {
  __shared__ ushort A[NPB][APAD];     // 10.5 KB
  __shared__ float  cmp[RREL * NB];
  __shared__ float  accO[NPB][2];
  int nb0 = blockIdx.x * NPB;
  int lane = threadIdx.x & 63, wid = threadIdx.x >> 6;

  if (threadIdx.x < RREL * NB) cmp[threadIdx.x] = compL[threadIdx.x];
  if (threadIdx.x < NPB * 2) accO[threadIdx.x >> 1][threadIdx.x & 1] = 0.f;
  {
    int t = threadIdx.x;
    int nl = t >> 4, c = (t & 15) * 4;
    int n = nb0 + nl;
    uint2 v = {0u, 0u};
    if (n < N) v = *(const uint2*)&hb_in[(size_t)n * HDIM + c];
    *(uint2*)&A[nl][c] = v;
  }
  __syncthreads();

  const ushort* hlane = hb_in + lane;
  for (int q = 0; q < 4; ++q) {
    int nl = wid * 4 + q;
    int n = nb0 + nl;
    if (n < N) {
      // boundaries: lanes 0..8 hold exact global offsets; others UINT_MAX
      uint bv = 0xFFFFFFFFu;
      if (lane < 9) bv = off8[(uint)n * RREL + (uint)lane];
      uint s0 = (uint)__builtin_amdgcn_readlane((int)bv, 0);
      uint s1 = (uint)__builtin_amdgcn_readlane((int)bv, 8);
      float run = 0.f, z0 = 0.f, z1 = 0.f, z2 = 0.f, z3 = 0.f;
      int rel = 0;
      uint prevb = s0;
      uint nextb = (uint)__builtin_amdgcn_readlane((int)bv, 1);
      for (uint base = s0; base < s1; base += 16u) {
        const uint* sp = sorted + base;
        uint4 w0 = *(const uint4*)(sp);
        uint4 w1 = *(const uint4*)(sp + 4);
        uint4 w2v = *(const uint4*)(sp + 8);
        uint4 w3 = *(const uint4*)(sp + 12);
        uint idx[16] = {w0.x, w0.y, w0.z, w0.w, w1.x, w1.y, w1.z, w1.w,
                        w2v.x, w2v.y, w2v.z, w2v.w, w3.x, w3.y, w3.z, w3.w};
        float g[16];
        #pragma unroll
        for (int j = 0; j < 16; ++j) {
          uint ij = (uint)__builtin_amdgcn_readfirstlane((int)idx[j]) & 0x1FFFFu;
          g[j] = bf2f(hlane[(size_t)ij << 6]);    // SGPR base + lane*2 voffset
        }
        uint m = s1 - base;                        // scalar
        #pragma unroll
        for (int j = 0; j < 16; ++j) {
          if ((uint)j < m) {                       // scalar guard
            uint pos = base + (uint)j;
            while (pos >= nextb) {                 // scalar flush walk -> z accum
              float mean = run * __builtin_amdgcn_rcpf(fmaxf((float)(nextb - prevb), 1.0f));
              f32x4 c4 = *(const f32x4*)&cmp[rel * NB];
              z0 += c4[0] * mean; z1 += c4[1] * mean;
              z2 += c4[2] * mean; z3 += c4[3] * mean;
              run = 0.f;
              ++rel;
              prevb = nextb;
              nextb = (uint)__builtin_amdgcn_readlane((int)bv, rel + 1);
            }
            run += g[j];
          }
        }
      }
      while (rel < RREL) {
        float mean = run * __builtin_amdgcn_rcpf(fmaxf((float)(nextb - prevb), 1.0f));
        f32x4 c4 = *(const f32x4*)&cmp[rel * NB];
        z0 += c4[0] * mean; z1 += c4[1] * mean;
        z2 += c4[2] * mean; z3 += c4[3] * mean;
        run = 0.f;
        ++rel;
        prevb = nextb;
        if (rel < RREL)
          nextb = (uint)__builtin_amdgcn_readlane((int)bv, rel + 1);
      }
      A[nl][HDIM + 0 * HDIM + lane] = f2bf(z0);
      A[nl][HDIM + 1 * HDIM + lane] = f2bf(z1);
      A[nl][HDIM + 2 * HDIM + lane] = f2bf(z2);
      A[nl][HDIM + 3 * HDIM + lane] = f2bf(z3);
    } else {
      #pragma unroll
      for (int b = 0; b < NB; ++b) A[nl][HDIM + b * HDIM + lane] = 0;
    }
  }
  __syncthreads();

  // MFMA: [16 x 320] @ [320 x 64]
  int m16 = lane & 15, khi = lane >> 4;
  int colbase = wid * 16;
  f32x4 acc = {0.f, 0.f, 0.f, 0.f};
  #pragma unroll
  for (int kk = 0; kk < KC2; kk += 32) {
    int k0 = kk + khi * 8;
    short8 av = *(const short8*)&A[m16][k0];
    short8 bv = *(const short8*)&wt[(uint)(colbase + m16) * KC2 + k0];
    acc = __builtin_amdgcn_mfma_f32_16x16x32_bf16(
        __builtin_bit_cast(bf16x8, av), __builtin_bit_cast(bf16x8, bv), acc, 0, 0, 0);
  }
  int j = colbase + m16;
  float bj = bias[j];
  if (!last) {
    #pragma unroll
    for (int r = 0; r < 4; ++r) {
      int nl = khi * 4 + r;
      int n = nb0 + nl;
      if (n < N) {
        float hs = bf2f(A[nl][j]);                 // self row (residual base)
        float hn = hs + fmaxf(acc[r] + bj, 0.f);
        hb_out[(uint)n * HDIM + j] = f2bf(hn);
      }
    }
  } else {
    // fused lin2: out[n] = h3[n] @ W2 + b2
    float w0 = w2[j * 2], w1 = w2[j * 2 + 1];
    #pragma unroll
    for (int r = 0; r < 4; ++r) {
      int nl = khi * 4 + r;
      int n = nb0 + nl;
      float hn = 0.f;
      if (n < N) {
        float hs = bf2f(A[nl][j]);
        hn = hs + fmaxf(acc[r] + bj, 0.f);
      }
      float p0 = hn * w0, p1 = hn * w1;
      #pragma unroll
      for (int o = 1; o < 16; o <<= 1) {
        p0 += __shfl_xor(p0, o);
        p1 += __shfl_xor(p1, o);
      }
      if (m16 == 0 && n < N) {
        atomicAdd(&accO[nl][0], p0);
        atomicAdd(&accO[nl][1], p1);
      }
    }
    __syncthreads();
    if (threadIdx.x < NPB * 2) {
      int nl = threadIdx.x >> 1, o = threadIdx.x & 1;
      int n = nb0 + nl;
      if (n < N) out[2 * n + o] = accO[nl][o] + b2[o];
    }
  }
}

extern "C" void kernel_launch(void* const* d_in, const int* in_sizes, int n_in,
                              void* d_out, int out_size, void* d_ws, size_t ws_size,
                              hipStream_t stream) {
  const float* x      = (const float*)d_in[0];
  const int*   ei     = (const int*)d_in[1];
  const int*   et     = (const int*)d_in[2];
  const float* lin1_w = (const float*)d_in[3];
  const float* lin1_b = (const float*)d_in[4];
  const float* bases  = (const float*)d_in[5];
  const float* comp   = (const float*)d_in[6];
  const float* root   = (const float*)d_in[7];
  const float* cbias  = (const float*)d_in[8];
  const float* lin2_w = (const float*)d_in[9];
  const float* lin2_b = (const float*)d_in[10];
  float* out = (float*)d_out;

  int N = in_sizes[0] / HDIM;
  int E = in_sizes[2];
  uint M8 = (uint)N * RREL;
  int NBK = (int)((M8 + 1023u) >> 10);    // <= 1024 for N <= 131072
  const int* srcp = ei;
  const int* dstp = ei + E;

  char* p = (char*)d_ws;
  auto carve = [&](size_t bytes) { char* r = p; p += (bytes + 255) & ~(size_t)255; return r; };
  ushort* hb_a    = (ushort*)carve((size_t)N * HDIM * 2);
  ushort* hb_b    = (ushort*)carve((size_t)N * HDIM * 2);
  uint*   sorted  = (uint*)carve((size_t)(E + 160) * 4);  // +160: chunk/preload overrun slack
  uint*   tmp     = (uint*)carve((size_t)E * 4);
  uint*   off8    = (uint*)carve((size_t)(M8 + 1) * 4);
  uint*   bcnt    = (uint*)carve(4096);
  uint*   boff    = (uint*)carve(4128);
  uint*   gcur    = (uint*)carve(4096);
  ushort* wt_lin1 = (ushort*)carve((size_t)HDIM * HDIM * 2);
  ushort* wt_conv = (ushort*)carve((size_t)2 * HDIM * KC2 * 2);
  carve((size_t)8 << 20);  // slack (masked-index gathers stay in ws)

  hipMemsetAsync(bcnt, 0, 4096, stream);

  int nwg = (N + NPB - 1) / NPB;

  k_prep_wt<<<(2 * HDIM * KC2 + 255) / 256, 256, 0, stream>>>(lin1_w, bases, root, wt_lin1, wt_conv);
  k_chist<<<128, 256, 0, stream>>>(dstp, et, E, bcnt);
  k_scanB<<<1, 1024, 0, stream>>>(bcnt, boff, gcur, off8, NBK, M8, (uint)E);
  k_cscat<<<128, 256, 0, stream>>>(srcp, dstp, et, E, gcur, tmp);
  k_fsort<<<NBK, 256, 0, stream>>>(boff, tmp, sorted, off8, M8);

  k_lin1<<<nwg, 256, 0, stream>>>(x, wt_lin1, lin1_b, hb_a, N);
  k_conv<<<nwg, 256, 0, stream>>>(off8, sorted, hb_a, comp, wt_conv, cbias,
                                  hb_b, N, 0, lin2_w, lin2_b, out);
  k_conv<<<nwg, 256, 0, stream>>>(off8, sorted, hb_b, comp + RREL * NB,
                                  wt_conv + HDIM * KC2, cbias + HDIM, hb_a, N, 1,
                                  lin2_w, lin2_b, out);
}